// Round 1
// baseline (1879.011 us; speedup 1.0000x reference)
//
#include <hip/hip_runtime.h>

// Problem constants
#define DIM    256
#define NWIN   294            // tokens per window = 6*7*7
#define BWIN   288            // windows = 2*12*12
#define MROWS  (BWIN * NWIN)  // 84672 total tokens
#define NHEADS 8
#define DH     32
#define NBIAS  1859           // 11*13*13

// ---------------------------------------------------------------------------
// Kernel 1: fused gather + QKV projection.
//   A = xt (84672 x 256) gathered from x (b,l,gx,gy,w1,w2,d)
//   C = A @ [Wq | Wkv] + [bq | bkv]   (84672 x 768)
//   Written as Q,K,V each in (B, h, n, dh) layout for the attention kernel.
// 64x64 tile, 256 threads, 4x4 acc per thread, K-chunks of 16.
// ---------------------------------------------------------------------------
__global__ __launch_bounds__(256) void qkv_gemm(
    const float* __restrict__ x,
    const float* __restrict__ Wq,  const float* __restrict__ bq,
    const float* __restrict__ Wkv, const float* __restrict__ bkv,
    float* __restrict__ Q, float* __restrict__ K, float* __restrict__ V)
{
    const int bn = blockIdx.x % 12;       // 12 col tiles of 64 (768 cols)
    const int bm = blockIdx.x / 12;       // 1323 row tiles (84672/64 exact)
    const int colBase = bn * 64;

    const float* W; const float* bias; int ldw, colOff;
    if (colBase < 256) { W = Wq;  bias = bq;  ldw = 256; colOff = colBase; }
    else               { W = Wkv; bias = bkv; ldw = 512; colOff = colBase - 256; }

    __shared__ float As[16][64];   // [kk][row]  (A transposed for vector reads)
    __shared__ float Ws[16][64];   // [kk][col]

    const int t  = threadIdx.x;
    const int tx = t & 15;         // col quad
    const int ty = t >> 4;         // row quad

    // --- A gather: thread loads float4 of row lr at k-offset lk each chunk
    const int lr = t >> 2;          // 0..63
    const int lk = (t & 3) * 4;     // 0,4,8,12
    {
        // nothing
    }
    const int m0   = bm * 64 + lr;
    const int bwin = m0 / NWIN;
    const int row  = m0 - bwin * NWIN;
    const int bb   = bwin / 144;
    const int r2   = bwin - bb * 144;
    const int gxi  = r2 / 12;
    const int gyi  = r2 - gxi * 12;
    const int lz   = row / 49;
    const int r3   = row - lz * 49;
    const int wa   = r3 / 7;
    const int wb   = r3 - wa * 7;
    const float* xrow = x + ((((((size_t)bb * 6 + lz) * 12 + gxi) * 12 + gyi) * 7 + wa) * 7 + wb) * DIM;

    // --- W load mapping
    const int wk = t >> 4;          // 0..15 (k within chunk)
    const int wc = (t & 15) * 4;    // col within tile

    float acc[4][4] = {};

    for (int k0 = 0; k0 < DIM; k0 += 16) {
        const float4 a4 = *(const float4*)(xrow + k0 + lk);
        const float4 w4 = *(const float4*)(W + (size_t)(k0 + wk) * ldw + colOff + wc);
        __syncthreads();
        As[lk + 0][lr] = a4.x;
        As[lk + 1][lr] = a4.y;
        As[lk + 2][lr] = a4.z;
        As[lk + 3][lr] = a4.w;
        *(float4*)(&Ws[wk][wc]) = w4;
        __syncthreads();
#pragma unroll
        for (int kk = 0; kk < 16; ++kk) {
            const float4 av = *(const float4*)(&As[kk][ty * 4]);
            const float4 wv = *(const float4*)(&Ws[kk][tx * 4]);
            acc[0][0] += av.x * wv.x; acc[0][1] += av.x * wv.y; acc[0][2] += av.x * wv.z; acc[0][3] += av.x * wv.w;
            acc[1][0] += av.y * wv.x; acc[1][1] += av.y * wv.y; acc[1][2] += av.y * wv.z; acc[1][3] += av.y * wv.w;
            acc[2][0] += av.z * wv.x; acc[2][1] += av.z * wv.y; acc[2][2] += av.z * wv.z; acc[2][3] += av.z * wv.w;
            acc[3][0] += av.w * wv.x; acc[3][1] += av.w * wv.y; acc[3][2] += av.w * wv.z; acc[3][3] += av.w * wv.w;
        }
    }

    // --- epilogue: bias add + scatter into Q/K/V (B,h,n,dh)
    const int c = colBase + tx * 4;     // global column 0..767 (quad-aligned, same head)
    float* dst; int ch;
    if      (c < 256) { dst = Q; ch = c; }
    else if (c < 512) { dst = K; ch = c - 256; }
    else              { dst = V; ch = c - 512; }
    const int hd = ch >> 5;
    const int di = ch & 31;
    const float4 bv = *(const float4*)(bias + colOff + tx * 4);

#pragma unroll
    for (int i = 0; i < 4; ++i) {
        const int mi = bm * 64 + ty * 4 + i;
        const int bw = mi / NWIN;
        const int rw = mi - bw * NWIN;
        float4 r;
        r.x = acc[i][0] + bv.x;
        r.y = acc[i][1] + bv.y;
        r.z = acc[i][2] + bv.z;
        r.w = acc[i][3] + bv.w;
        *(float4*)(dst + ((size_t)(bw * NHEADS + hd) * NWIN + rw) * DH + di) = r;
    }
}

// ---------------------------------------------------------------------------
// Kernel 2: fused attention per (window, head). Online softmax, one thread per
// query row. K staged in LDS; V read via block-uniform global loads (L1-hot);
// relative-position bias computed as biasH[c_i - c_j + 929].
// ---------------------------------------------------------------------------
__global__ __launch_bounds__(320) void attn_kernel(
    const float* __restrict__ Q, const float* __restrict__ Kbuf,
    const float* __restrict__ Vbuf, const float* __restrict__ bias_table,
    float* __restrict__ O)
{
    const int bh   = blockIdx.x;      // 0..2303
    const int bwin = bh >> 3;
    const int h    = bh & 7;

    __shared__ float Ks[NWIN * DH];   // 37632 B
    __shared__ float biasH[NBIAS];    // 7436 B
    __shared__ int   cIdx[NWIN];      // 1176 B

    const int t = threadIdx.x;
    const float* Kg = Kbuf + (size_t)bh * NWIN * DH;
    for (int i = t; i < NWIN * DH; i += 320) Ks[i] = Kg[i];
    for (int i = t; i < NBIAS; i += 320)     biasH[i] = bias_table[i * NHEADS + h];
    for (int i = t; i < NWIN; i += 320) {
        const int l = i / 49, r = i - l * 49;
        cIdx[i] = 169 * l + 13 * (r / 7) + (r - (r / 7) * 7);
    }
    __syncthreads();

    if (t >= NWIN) return;

    float q[DH];
    const float* qp = Q + ((size_t)bh * NWIN + t) * DH;
#pragma unroll
    for (int d = 0; d < DH; d += 4) {
        const float4 f = *(const float4*)(qp + d);
        q[d] = f.x; q[d + 1] = f.y; q[d + 2] = f.z; q[d + 3] = f.w;
    }

    const int   ci    = cIdx[t] + 929;
    const float scale = 0.17677669529663687f;   // 1/sqrt(32)
    const float* Vg   = Vbuf + (size_t)bh * NWIN * DH;

    float o[DH] = {};
    float mval = -1e30f, lsum = 0.f;

    for (int j = 0; j < NWIN; ++j) {
        float s = 0.f;
#pragma unroll
        for (int d = 0; d < DH; ++d) s += q[d] * Ks[j * DH + d];
        s = s * scale + biasH[ci - cIdx[j]];

        const float mNew = fmaxf(mval, s);
        const float p    = __expf(s - mNew);
        if (mNew > mval) {
            const float alpha = __expf(mval - mNew);
            lsum *= alpha;
#pragma unroll
            for (int d = 0; d < DH; ++d) o[d] *= alpha;
            mval = mNew;
        }
        lsum += p;
#pragma unroll
        for (int d = 0; d < DH; d += 4) {
            const float4 v = *(const float4*)(Vg + j * DH + d);
            o[d]     += p * v.x;
            o[d + 1] += p * v.y;
            o[d + 2] += p * v.z;
            o[d + 3] += p * v.w;
        }
    }

    const float inv = 1.0f / lsum;
    float* op = O + ((size_t)bwin * NWIN + t) * DIM + h * DH;
#pragma unroll
    for (int d = 0; d < DH; d += 4) {
        float4 r;
        r.x = o[d] * inv; r.y = o[d + 1] * inv; r.z = o[d + 2] * inv; r.w = o[d + 3] * inv;
        *(float4*)(op + d) = r;
    }
}

// ---------------------------------------------------------------------------
// Kernel 3: output projection + scatter to (b,l,gx,gy,w1,w2,d).
//   out = O (84672 x 256) @ Wout (256 x 256), no bias.
// ---------------------------------------------------------------------------
__global__ __launch_bounds__(256) void out_gemm(
    const float* __restrict__ O, const float* __restrict__ Wout,
    float* __restrict__ out)
{
    const int bn = blockIdx.x % 4;       // 4 col tiles (256 cols)
    const int bm = blockIdx.x / 4;       // 1323 row tiles
    const int colBase = bn * 64;

    __shared__ float As[16][64];
    __shared__ float Ws[16][64];

    const int t  = threadIdx.x;
    const int tx = t & 15;
    const int ty = t >> 4;

    const int lr = t >> 2;
    const int lk = (t & 3) * 4;
    const float* arow = O + (size_t)(bm * 64 + lr) * DIM;

    const int wk = t >> 4;
    const int wc = (t & 15) * 4;

    float acc[4][4] = {};

    for (int k0 = 0; k0 < DIM; k0 += 16) {
        const float4 a4 = *(const float4*)(arow + k0 + lk);
        const float4 w4 = *(const float4*)(Wout + (size_t)(k0 + wk) * DIM + colBase + wc);
        __syncthreads();
        As[lk + 0][lr] = a4.x;
        As[lk + 1][lr] = a4.y;
        As[lk + 2][lr] = a4.z;
        As[lk + 3][lr] = a4.w;
        *(float4*)(&Ws[wk][wc]) = w4;
        __syncthreads();
#pragma unroll
        for (int kk = 0; kk < 16; ++kk) {
            const float4 av = *(const float4*)(&As[kk][ty * 4]);
            const float4 wv = *(const float4*)(&Ws[kk][tx * 4]);
            acc[0][0] += av.x * wv.x; acc[0][1] += av.x * wv.y; acc[0][2] += av.x * wv.z; acc[0][3] += av.x * wv.w;
            acc[1][0] += av.y * wv.x; acc[1][1] += av.y * wv.y; acc[1][2] += av.y * wv.z; acc[1][3] += av.y * wv.w;
            acc[2][0] += av.z * wv.x; acc[2][1] += av.z * wv.y; acc[2][2] += av.z * wv.z; acc[2][3] += av.z * wv.w;
            acc[3][0] += av.w * wv.x; acc[3][1] += av.w * wv.y; acc[3][2] += av.w * wv.z; acc[3][3] += av.w * wv.w;
        }
    }

#pragma unroll
    for (int i = 0; i < 4; ++i) {
        const int mi = bm * 64 + ty * 4 + i;
        const int bw = mi / NWIN;
        const int rw = mi - bw * NWIN;
        const int bb  = bw / 144;
        const int r2  = bw - bb * 144;
        const int gxi = r2 / 12;
        const int gyi = r2 - gxi * 12;
        const int lz  = rw / 49;
        const int r3  = rw - lz * 49;
        const int wa  = r3 / 7;
        const int wb  = r3 - wa * 7;
        const size_t off = ((((((size_t)bb * 6 + lz) * 12 + gxi) * 12 + gyi) * 7 + wa) * 7 + wb) * DIM
                         + colBase + tx * 4;
        float4 r;
        r.x = acc[i][0]; r.y = acc[i][1]; r.z = acc[i][2]; r.w = acc[i][3];
        *(float4*)(out + off) = r;
    }
}

// ---------------------------------------------------------------------------
extern "C" void kernel_launch(void* const* d_in, const int* in_sizes, int n_in,
                              void* d_out, int out_size, void* d_ws, size_t ws_size,
                              hipStream_t stream)
{
    const float* x          = (const float*)d_in[0];
    const float* Wq         = (const float*)d_in[1];
    const float* bq         = (const float*)d_in[2];
    const float* Wkv        = (const float*)d_in[3];
    const float* bkv        = (const float*)d_in[4];
    const float* Wout       = (const float*)d_in[5];
    const float* bias_table = (const float*)d_in[6];
    float* out = (float*)d_out;

    const size_t planeSz = (size_t)MROWS * DIM;   // 21,676,032 floats
    float* Q = (float*)d_ws;
    float* K = Q + planeSz;
    float* V = K + planeSz;
    float* O = V + planeSz;

    qkv_gemm<<<1323 * 12, 256, 0, stream>>>(x, Wq, bq, Wkv, bkv, Q, K, V);
    attn_kernel<<<BWIN * NHEADS, 320, 0, stream>>>(Q, K, V, bias_table, O);
    out_gemm<<<1323 * 4, 256, 0, stream>>>(O, Wout, out);
}

// Round 2
// 909.830 us; speedup vs baseline: 2.0652x; 2.0652x over previous
//
#include <hip/hip_runtime.h>

// Problem constants
#define DIM    256
#define NWIN   294            // tokens per window = 6*7*7
#define BWIN   288            // windows = 2*12*12
#define MROWS  (BWIN * NWIN)  // 84672 total tokens
#define NHEADS 8
#define DH     32
#define NBIAS  1859           // 11*13*13

typedef __attribute__((ext_vector_type(8))) short  short8;  // 8 bf16 = 4 VGPRs
typedef __attribute__((ext_vector_type(4))) float  f32x4;

__device__ __forceinline__ unsigned short f2bf(float f) {
    unsigned int u = __float_as_uint(f);
    u += 0x7FFFu + ((u >> 16) & 1u);     // round-to-nearest-even
    return (unsigned short)(u >> 16);
}

// ---------------------------------------------------------------------------
// Kernel 1: fused gather + QKV projection (fp32 math).
//   Emits Q, K as bf16 (B,h,n,dh) row-major; V as bf16 transposed (B,h,dh,n).
// ---------------------------------------------------------------------------
__global__ __launch_bounds__(256) void qkv_gemm(
    const float* __restrict__ x,
    const float* __restrict__ Wq,  const float* __restrict__ bq,
    const float* __restrict__ Wkv, const float* __restrict__ bkv,
    unsigned short* __restrict__ Qb, unsigned short* __restrict__ Kb,
    unsigned short* __restrict__ Vtb)
{
    const int bn = blockIdx.x % 12;       // 12 col tiles of 64 (768 cols)
    const int bm = blockIdx.x / 12;       // 1323 row tiles
    const int colBase = bn * 64;

    const float* W; const float* bias; int ldw, colOff;
    if (colBase < 256) { W = Wq;  bias = bq;  ldw = 256; colOff = colBase; }
    else               { W = Wkv; bias = bkv; ldw = 512; colOff = colBase - 256; }

    __shared__ float As[16][64];
    __shared__ float Ws[16][64];

    const int t  = threadIdx.x;
    const int tx = t & 15;
    const int ty = t >> 4;

    const int lr = t >> 2;
    const int lk = (t & 3) * 4;
    const int m0   = bm * 64 + lr;
    const int bwin = m0 / NWIN;
    const int row  = m0 - bwin * NWIN;
    const int bb   = bwin / 144;
    const int r2   = bwin - bb * 144;
    const int gxi  = r2 / 12;
    const int gyi  = r2 - gxi * 12;
    const int lz   = row / 49;
    const int r3   = row - lz * 49;
    const int wa   = r3 / 7;
    const int wb   = r3 - wa * 7;
    const float* xrow = x + ((((((size_t)bb * 6 + lz) * 12 + gxi) * 12 + gyi) * 7 + wa) * 7 + wb) * DIM;

    const int wk = t >> 4;
    const int wc = (t & 15) * 4;

    float acc[4][4] = {};

    for (int k0 = 0; k0 < DIM; k0 += 16) {
        const float4 a4 = *(const float4*)(xrow + k0 + lk);
        const float4 w4 = *(const float4*)(W + (size_t)(k0 + wk) * ldw + colOff + wc);
        __syncthreads();
        As[lk + 0][lr] = a4.x;
        As[lk + 1][lr] = a4.y;
        As[lk + 2][lr] = a4.z;
        As[lk + 3][lr] = a4.w;
        *(float4*)(&Ws[wk][wc]) = w4;
        __syncthreads();
#pragma unroll
        for (int kk = 0; kk < 16; ++kk) {
            const float4 av = *(const float4*)(&As[kk][ty * 4]);
            const float4 wv = *(const float4*)(&Ws[kk][tx * 4]);
            acc[0][0] += av.x * wv.x; acc[0][1] += av.x * wv.y; acc[0][2] += av.x * wv.z; acc[0][3] += av.x * wv.w;
            acc[1][0] += av.y * wv.x; acc[1][1] += av.y * wv.y; acc[1][2] += av.y * wv.z; acc[1][3] += av.y * wv.w;
            acc[2][0] += av.z * wv.x; acc[2][1] += av.z * wv.y; acc[2][2] += av.z * wv.z; acc[2][3] += av.z * wv.w;
            acc[3][0] += av.w * wv.x; acc[3][1] += av.w * wv.y; acc[3][2] += av.w * wv.z; acc[3][3] += av.w * wv.w;
        }
    }

    // --- epilogue: bias add + bf16 convert + scatter
    const int c = colBase + tx * 4;
    int ch, which;
    if      (c < 256) { ch = c;       which = 0; }
    else if (c < 512) { ch = c - 256; which = 1; }
    else              { ch = c - 512; which = 2; }
    const int hd = ch >> 5;
    const int di = ch & 31;
    const float4 bv = *(const float4*)(bias + colOff + tx * 4);

#pragma unroll
    for (int i = 0; i < 4; ++i) {
        const int mi = bm * 64 + ty * 4 + i;
        const int bw = mi / NWIN;
        const int rw = mi - bw * NWIN;
        const unsigned short b0 = f2bf(acc[i][0] + bv.x);
        const unsigned short b1 = f2bf(acc[i][1] + bv.y);
        const unsigned short b2 = f2bf(acc[i][2] + bv.z);
        const unsigned short b3 = f2bf(acc[i][3] + bv.w);
        if (which == 2) {
            // V transposed: (B,h,dh,n)
            const size_t base = ((size_t)(bw * NHEADS + hd) * DH + di) * NWIN + rw;
            Vtb[base]            = b0;
            Vtb[base + NWIN]     = b1;
            Vtb[base + 2 * NWIN] = b2;
            Vtb[base + 3 * NWIN] = b3;
        } else {
            unsigned short* dst = (which == 0) ? Qb : Kb;
            uint2 pk;
            pk.x = (unsigned int)b0 | ((unsigned int)b1 << 16);
            pk.y = (unsigned int)b2 | ((unsigned int)b3 << 16);
            *(uint2*)(dst + ((size_t)(bw * NHEADS + hd) * NWIN + rw) * DH + di) = pk;
        }
    }
}

// ---------------------------------------------------------------------------
// Kernel 2: MFMA flash attention, one block per (window, head).
//   4 waves; wave w handles i-tiles {w, w+4, ...} (19 tiles of 16 rows, 294 pad 304).
//   S row-block (16 x 304) held in registers (19 x f32x4 per lane).
// ---------------------------------------------------------------------------
__global__ __launch_bounds__(256, 3) void attn_kernel(
    const unsigned short* __restrict__ Qb, const unsigned short* __restrict__ Kb,
    const unsigned short* __restrict__ Vtb, const float* __restrict__ bias_table,
    float* __restrict__ O)
{
    const int bh   = blockIdx.x;      // 0..2303
    const int bwin = bh >> 3;
    const int h    = bh & 7;

    __shared__ unsigned short Ks[304 * 32];        // 19456 B, row-major keys
    __shared__ unsigned short Vts[32 * 328];       // 20992 B, V^T padded pitch
    __shared__ unsigned short Pc[4 * 16 * 32];     // 4096 B, per-wave P chunk
    __shared__ float          biasH[NBIAS];        // 7436 B
    __shared__ unsigned short cIdx[304];           // 608 B

    const int t    = threadIdx.x;
    const int w    = t >> 6;
    const int lane = t & 63;
    const int quad = lane >> 4;
    const int l15  = lane & 15;

    // ---- stage K (contiguous 16B chunks), zero pad rows 294..303
    {
        const uint4* Kg4 = (const uint4*)(Kb + (size_t)bh * (NWIN * DH));
        for (int i = t; i < (NWIN * DH) / 8; i += 256) ((uint4*)Ks)[i] = Kg4[i];
        for (int i = NWIN * DH + t; i < 304 * 32; i += 256) Ks[i] = 0;
    }
    // ---- stage V^T with zero pad cols
    {
        const unsigned short* Vg = Vtb + (size_t)bh * (DH * NWIN);
        for (int i = t; i < 32 * 328; i += 256) {
            const int r = i / 328, c = i - r * 328;
            Vts[i] = (c < NWIN) ? Vg[r * NWIN + c] : (unsigned short)0;
        }
    }
    // ---- stage bias column for this head
    for (int i = t; i < NBIAS; i += 256) biasH[i] = bias_table[i * NHEADS + h];
    // ---- coordinate codes (0 for pad rows)
    for (int i = t; i < 304; i += 256) {
        if (i < NWIN) {
            const int l = i / 49, r = i - l * 49;
            cIdx[i] = (unsigned short)(169 * l + 13 * (r / 7) + (r - (r / 7) * 7));
        } else cIdx[i] = 0;
    }
    __syncthreads();

    const float scale = 0.17677669529663687f;   // 1/sqrt(32)
    const unsigned short* Qg = Qb + (size_t)bh * (NWIN * DH);
    unsigned short* Pw = Pc + w * (16 * 32);

#pragma unroll
    for (int r5 = 0; r5 < 5; ++r5) {
        const int it = 4 * r5 + w;
        if (it < 19) {
            // ---- load Q A-fragment (zero for pad rows)
            short8 qf;
            const int qrow = it * 16 + l15;
            if (qrow < NWIN) qf = *(const short8*)(Qg + qrow * DH + quad * 8);
            else             qf = (short8){0,0,0,0,0,0,0,0};

            // ---- S = Q K^T : 19 MFMAs, full row-block in registers
            f32x4 S[19];
#pragma unroll
            for (int jt = 0; jt < 19; ++jt) {
                const short8 bf = *(const short8*)(Ks + (jt * 16 + l15) * 32 + quad * 8);
                S[jt] = __builtin_amdgcn_mfma_f32_16x16x32_bf16(qf, bf, (f32x4){0.f,0.f,0.f,0.f}, 0, 0, 0);
            }

            // ---- hoist column codes
            int cj[19];
#pragma unroll
            for (int jt = 0; jt < 19; ++jt) cj[jt] = cIdx[jt * 16 + l15];

            // ---- softmax per row (rows quad*4+r, cols spread over 16 lanes)
            const int rowb = it * 16 + quad * 4;
            float inv[4];
#pragma unroll
            for (int r = 0; r < 4; ++r) {
                const int ci = (int)cIdx[rowb + r] + 929;
                float m = -1e30f;
#pragma unroll
                for (int jt = 0; jt < 19; ++jt) {
                    float s = S[jt][r] * scale + biasH[ci - cj[jt]];
                    if (jt == 18 && l15 >= 6) s = -1e30f;   // cols >= 294
                    S[jt][r] = s;
                    m = fmaxf(m, s);
                }
                m = fmaxf(m, __shfl_xor(m, 1));
                m = fmaxf(m, __shfl_xor(m, 2));
                m = fmaxf(m, __shfl_xor(m, 4));
                m = fmaxf(m, __shfl_xor(m, 8));
                float lsum = 0.f;
#pragma unroll
                for (int jt = 0; jt < 19; ++jt) {
                    const float p = __expf(S[jt][r] - m);
                    S[jt][r] = p;
                    lsum += p;
                }
                lsum += __shfl_xor(lsum, 1);
                lsum += __shfl_xor(lsum, 2);
                lsum += __shfl_xor(lsum, 4);
                lsum += __shfl_xor(lsum, 8);
                inv[r] = 1.0f / lsum;
            }

            // ---- O = P V : D-layout -> A-layout via per-wave LDS chunk
            f32x4 o0 = {0.f,0.f,0.f,0.f}, o1 = {0.f,0.f,0.f,0.f};
#pragma unroll
            for (int kt = 0; kt < 10; ++kt) {
                const int jt0 = 2 * kt, jt1 = 2 * kt + 1;
#pragma unroll
                for (int r = 0; r < 4; ++r) {
                    Pw[(quad * 4 + r) * 32 + l15]      = f2bf(S[jt0][r]);
                    Pw[(quad * 4 + r) * 32 + 16 + l15] = (jt1 < 19) ? f2bf(S[jt1][r]) : (unsigned short)0;
                }
                __asm__ volatile("s_waitcnt lgkmcnt(0)" ::: "memory");
                const short8 pa = *(const short8*)(Pw + l15 * 32 + quad * 8);
                const short8 v0 = *(const short8*)(Vts + l15 * 328 + kt * 32 + quad * 8);
                const short8 v1 = *(const short8*)(Vts + (16 + l15) * 328 + kt * 32 + quad * 8);
                o0 = __builtin_amdgcn_mfma_f32_16x16x32_bf16(pa, v0, o0, 0, 0, 0);
                o1 = __builtin_amdgcn_mfma_f32_16x16x32_bf16(pa, v1, o1, 0, 0, 0);
                __asm__ volatile("s_waitcnt lgkmcnt(0)" ::: "memory");
            }

            // ---- normalize + store (fp32 O, (B*n, 256) rows)
#pragma unroll
            for (int r = 0; r < 4; ++r) {
                const int rg = it * 16 + quad * 4 + r;
                if (rg < NWIN) {
                    float* op = O + ((size_t)bwin * NWIN + rg) * DIM + h * DH;
                    op[l15]      = o0[r] * inv[r];
                    op[16 + l15] = o1[r] * inv[r];
                }
            }
        }
    }
}

// ---------------------------------------------------------------------------
// Kernel 3: output projection + scatter to (b,l,gx,gy,w1,w2,d).
// ---------------------------------------------------------------------------
__global__ __launch_bounds__(256) void out_gemm(
    const float* __restrict__ O, const float* __restrict__ Wout,
    float* __restrict__ out)
{
    const int bn = blockIdx.x % 4;
    const int bm = blockIdx.x / 4;
    const int colBase = bn * 64;

    __shared__ float As[16][64];
    __shared__ float Ws[16][64];

    const int t  = threadIdx.x;
    const int tx = t & 15;
    const int ty = t >> 4;

    const int lr = t >> 2;
    const int lk = (t & 3) * 4;
    const float* arow = O + (size_t)(bm * 64 + lr) * DIM;

    const int wk = t >> 4;
    const int wc = (t & 15) * 4;

    float acc[4][4] = {};

    for (int k0 = 0; k0 < DIM; k0 += 16) {
        const float4 a4 = *(const float4*)(arow + k0 + lk);
        const float4 w4 = *(const float4*)(Wout + (size_t)(k0 + wk) * DIM + colBase + wc);
        __syncthreads();
        As[lk + 0][lr] = a4.x;
        As[lk + 1][lr] = a4.y;
        As[lk + 2][lr] = a4.z;
        As[lk + 3][lr] = a4.w;
        *(float4*)(&Ws[wk][wc]) = w4;
        __syncthreads();
#pragma unroll
        for (int kk = 0; kk < 16; ++kk) {
            const float4 av = *(const float4*)(&As[kk][ty * 4]);
            const float4 wv = *(const float4*)(&Ws[kk][tx * 4]);
            acc[0][0] += av.x * wv.x; acc[0][1] += av.x * wv.y; acc[0][2] += av.x * wv.z; acc[0][3] += av.x * wv.w;
            acc[1][0] += av.y * wv.x; acc[1][1] += av.y * wv.y; acc[1][2] += av.y * wv.z; acc[1][3] += av.y * wv.w;
            acc[2][0] += av.z * wv.x; acc[2][1] += av.z * wv.y; acc[2][2] += av.z * wv.z; acc[2][3] += av.z * wv.w;
            acc[3][0] += av.w * wv.x; acc[3][1] += av.w * wv.y; acc[3][2] += av.w * wv.z; acc[3][3] += av.w * wv.w;
        }
    }

#pragma unroll
    for (int i = 0; i < 4; ++i) {
        const int mi = bm * 64 + ty * 4 + i;
        const int bw = mi / NWIN;
        const int rw = mi - bw * NWIN;
        const int bb  = bw / 144;
        const int r2  = bw - bb * 144;
        const int gxi = r2 / 12;
        const int gyi = r2 - gxi * 12;
        const int lz  = rw / 49;
        const int r3  = rw - lz * 49;
        const int wa  = r3 / 7;
        const int wb  = r3 - wa * 7;
        const size_t off = ((((((size_t)bb * 6 + lz) * 12 + gxi) * 12 + gyi) * 7 + wa) * 7 + wb) * DIM
                         + colBase + tx * 4;
        float4 r;
        r.x = acc[i][0]; r.y = acc[i][1]; r.z = acc[i][2]; r.w = acc[i][3];
        *(float4*)(out + off) = r;
    }
}

// ---------------------------------------------------------------------------
extern "C" void kernel_launch(void* const* d_in, const int* in_sizes, int n_in,
                              void* d_out, int out_size, void* d_ws, size_t ws_size,
                              hipStream_t stream)
{
    const float* x          = (const float*)d_in[0];
    const float* Wq         = (const float*)d_in[1];
    const float* bq         = (const float*)d_in[2];
    const float* Wkv        = (const float*)d_in[3];
    const float* bkv        = (const float*)d_in[4];
    const float* Wout       = (const float*)d_in[5];
    const float* bias_table = (const float*)d_in[6];
    float* out = (float*)d_out;

    const size_t planeU = (size_t)MROWS * DIM;    // 21,676,032 elems per tensor
    unsigned short* Qb  = (unsigned short*)d_ws;
    unsigned short* Kb  = Qb + planeU;
    unsigned short* Vtb = Kb + planeU;
    float*          O   = (float*)(Vtb + planeU);

    qkv_gemm<<<1323 * 12, 256, 0, stream>>>(x, Wq, bq, Wkv, bkv, Qb, Kb, Vtb);
    attn_kernel<<<BWIN * NHEADS, 256, 0, stream>>>(Qb, Kb, Vtb, bias_table, O);
    out_gemm<<<1323 * 4, 256, 0, stream>>>(O, Wout, out);
}

// Round 3
// 443.779 us; speedup vs baseline: 4.2341x; 2.0502x over previous
//
#include <hip/hip_runtime.h>

// Problem constants
#define DIM    256
#define NWIN   294            // tokens per window = 6*7*7
#define BWIN   288            // windows = 2*12*12
#define MROWS  (BWIN * NWIN)  // 84672 total tokens
#define MPAD   84736          // 662 * 128 (M padded for 128-row tiles)
#define NHEADS 8
#define DH     32
#define NBIAS  1859           // 11*13*13

typedef __attribute__((ext_vector_type(8))) short  short8;  // 8 bf16 = 4 VGPRs
typedef __attribute__((ext_vector_type(4))) float  f32x4;

__device__ __forceinline__ unsigned short f2bf(float f) {
    unsigned int u = __float_as_uint(f);
    u += 0x7FFFu + ((u >> 16) & 1u);     // round-to-nearest-even
    return (unsigned short)(u >> 16);
}

// async global->LDS, 16B per lane. LDS dest = wave-uniform base + lane*16.
__device__ __forceinline__ void gl_lds16(const void* g, void* l) {
    __builtin_amdgcn_global_load_lds((const __attribute__((address_space(1))) unsigned int*)g,
                                     (__attribute__((address_space(3))) unsigned int*)l,
                                     16, 0, 0);
}

// ---------------------------------------------------------------------------
// Prep A: gather + cast x -> Xb bf16 (MPAD x 256) row-major in (B*n, d) order.
// One thread per 8 elements. Pad rows zeroed.
// ---------------------------------------------------------------------------
__global__ __launch_bounds__(256) void prep_x(const float* __restrict__ x,
                                              unsigned short* __restrict__ Xb)
{
    const int g   = blockIdx.x * 256 + threadIdx.x;
    const int row = g >> 5;              // 32 groups of 8 per 256-col row
    const int col = (g & 31) * 8;
    if (row >= MPAD) return;
    uint4 pk;
    if (row < MROWS) {
        const int bw = row / NWIN, rw = row - bw * NWIN;
        const int bb = bw / 144,  r2 = bw - bb * 144;
        const int gxi = r2 / 12,  gyi = r2 - gxi * 12;
        const int lz = rw / 49,   r3 = rw - lz * 49;
        const int wa = r3 / 7,    wb = r3 - wa * 7;
        const float* src = x + ((((((size_t)bb * 6 + lz) * 12 + gxi) * 12 + gyi) * 7 + wa) * 7 + wb) * DIM + col;
        const float4 f0 = *(const float4*)(src);
        const float4 f1 = *(const float4*)(src + 4);
        pk.x = (unsigned)f2bf(f0.x) | ((unsigned)f2bf(f0.y) << 16);
        pk.y = (unsigned)f2bf(f0.z) | ((unsigned)f2bf(f0.w) << 16);
        pk.z = (unsigned)f2bf(f1.x) | ((unsigned)f2bf(f1.y) << 16);
        pk.w = (unsigned)f2bf(f1.z) | ((unsigned)f2bf(f1.w) << 16);
    } else {
        pk = (uint4){0u, 0u, 0u, 0u};
    }
    *(uint4*)(Xb + (size_t)row * 256 + col) = pk;
}

// ---------------------------------------------------------------------------
// Prep B: cast + transpose weights to (N,K) bf16 so B-fragments are contiguous.
//   Wt  (768,256): rows 0..255 = Wq cols, rows 256..767 = Wkv cols
//   Wot (256,256): Wout transposed
// ---------------------------------------------------------------------------
__global__ __launch_bounds__(256) void prep_w(const float* __restrict__ Wq,
                                              const float* __restrict__ Wkv,
                                              const float* __restrict__ Wout,
                                              unsigned short* __restrict__ Wt,
                                              unsigned short* __restrict__ Wot)
{
    const int g = blockIdx.x * 256 + threadIdx.x;
    if (g < 768 * 256) {
        const int n = g >> 8, k = g & 255;
        const float v = (n < 256) ? Wq[k * 256 + n] : Wkv[k * 512 + (n - 256)];
        Wt[g] = f2bf(v);
    } else {
        const int g2 = g - 768 * 256;
        const int n = g2 >> 8, k = g2 & 255;
        Wot[g2] = f2bf(Wout[k * 256 + n]);
    }
}

// ---------------------------------------------------------------------------
// Kernel 1: QKV projection, bf16 MFMA (m97 structure).
//   C(MPAD x 768) = Xb @ Wt^T ; epilogue: +bias, bf16, scatter to Q/K/V^T.
// 128x128 tile, BK=64, 4 waves, 4x4 16x16 frags per wave.
// ---------------------------------------------------------------------------
__global__ __launch_bounds__(256) void gemm_qkv(
    const unsigned short* __restrict__ Xb, const unsigned short* __restrict__ Wt,
    const float* __restrict__ bq, const float* __restrict__ bkv,
    unsigned short* __restrict__ Qb, unsigned short* __restrict__ Kb,
    unsigned short* __restrict__ Vtb)
{
    __shared__ __align__(16) unsigned short As[128 * 64];  // 16 KB
    __shared__ __align__(16) unsigned short Bs[128 * 64];  // 16 KB

    const int bn = blockIdx.x % 6;
    const int bm = blockIdx.x / 6;
    const int tileM = bm * 128;
    const int tileN = bn * 128;

    const int t    = threadIdx.x;
    const int w    = t >> 6;
    const int lane = t & 63;
    const int quad = lane >> 4;
    const int l15  = lane & 15;
    const int wm   = w >> 1, wn = w & 1;

    // staging: chunk c = w*4+i covers rows c*8..c*8+7 (64 k-cols each)
    const int rA = lane >> 3;            // row within chunk
    const int kA = (lane & 7) * 8;       // k-col (elems)
    const unsigned short* aBase = Xb + ((size_t)tileM + rA) * 256 + kA;
    const unsigned short* bBase = Wt + ((size_t)tileN + rA) * 256 + kA;

    f32x4 acc[4][4] = {};

    for (int kb = 0; kb < 4; ++kb) {
        const int k0 = kb * 64;
        __syncthreads();
#pragma unroll
        for (int i = 0; i < 4; ++i) {
            const int c = w * 4 + i;
            gl_lds16(aBase + (size_t)c * 8 * 256 + k0, &As[c * 512]);
            gl_lds16(bBase + (size_t)c * 8 * 256 + k0, &Bs[c * 512]);
        }
        __syncthreads();
#pragma unroll
        for (int c2 = 0; c2 < 2; ++c2) {
            const int kk = c2 * 32 + quad * 8;
            short8 a[4], b[4];
#pragma unroll
            for (int mi = 0; mi < 4; ++mi)
                a[mi] = *(const short8*)&As[(wm * 64 + mi * 16 + l15) * 64 + kk];
#pragma unroll
            for (int ni = 0; ni < 4; ++ni)
                b[ni] = *(const short8*)&Bs[(wn * 64 + ni * 16 + l15) * 64 + kk];
#pragma unroll
            for (int mi = 0; mi < 4; ++mi)
#pragma unroll
                for (int ni = 0; ni < 4; ++ni)
                    acc[mi][ni] = __builtin_amdgcn_mfma_f32_16x16x32_bf16(a[mi], b[ni], acc[mi][ni], 0, 0, 0);
        }
    }

    // ---- epilogue: bias + bf16 + scatter
    const int colB = tileN + wn * 64;
    float bias[4];
#pragma unroll
    for (int ni = 0; ni < 4; ++ni) {
        const int n = colB + ni * 16 + l15;
        bias[ni] = (n < 256) ? bq[n] : bkv[n - 256];
    }
    const int rowB = tileM + wm * 64 + quad * 4;
#pragma unroll
    for (int mi = 0; mi < 4; ++mi) {
#pragma unroll
        for (int r = 0; r < 4; ++r) {
            const int row = rowB + mi * 16 + r;
            if (row < MROWS) {
                const int bw = row / NWIN;
                const int rw = row - bw * NWIN;
#pragma unroll
                for (int ni = 0; ni < 4; ++ni) {
                    const int n = colB + ni * 16 + l15;
                    const unsigned short v = f2bf(acc[mi][ni][r] + bias[ni]);
                    const int ch = n & 255;
                    const int hd = ch >> 5, di = ch & 31;
                    if (n < 512) {
                        unsigned short* dst = (n < 256) ? Qb : Kb;
                        dst[((size_t)(bw * NHEADS + hd) * NWIN + rw) * DH + di] = v;
                    } else {
                        Vtb[((size_t)(bw * NHEADS + hd) * DH + di) * NWIN + rw] = v;
                    }
                }
            }
        }
    }
}

// ---------------------------------------------------------------------------
// Kernel 2: MFMA flash attention, one block per (window, head). (unchanged
// from R2 except O is written as bf16 for the MFMA out-projection.)
// ---------------------------------------------------------------------------
__global__ __launch_bounds__(256, 3) void attn_kernel(
    const unsigned short* __restrict__ Qb, const unsigned short* __restrict__ Kb,
    const unsigned short* __restrict__ Vtb, const float* __restrict__ bias_table,
    unsigned short* __restrict__ Ob)
{
    const int bh   = blockIdx.x;      // 0..2303
    const int bwin = bh >> 3;
    const int h    = bh & 7;

    __shared__ __align__(16) unsigned short Ks[304 * 32];
    __shared__ __align__(16) unsigned short Vts[32 * 328];
    __shared__ __align__(16) unsigned short Pc[4 * 16 * 32];
    __shared__ float          biasH[NBIAS];
    __shared__ unsigned short cIdx[304];

    const int t    = threadIdx.x;
    const int w    = t >> 6;
    const int lane = t & 63;
    const int quad = lane >> 4;
    const int l15  = lane & 15;

    {
        const uint4* Kg4 = (const uint4*)(Kb + (size_t)bh * (NWIN * DH));
        for (int i = t; i < (NWIN * DH) / 8; i += 256) ((uint4*)Ks)[i] = Kg4[i];
        for (int i = NWIN * DH + t; i < 304 * 32; i += 256) Ks[i] = 0;
    }
    {
        const unsigned short* Vg = Vtb + (size_t)bh * (DH * NWIN);
        for (int i = t; i < 32 * 328; i += 256) {
            const int r = i / 328, c = i - r * 328;
            Vts[i] = (c < NWIN) ? Vg[r * NWIN + c] : (unsigned short)0;
        }
    }
    for (int i = t; i < NBIAS; i += 256) biasH[i] = bias_table[i * NHEADS + h];
    for (int i = t; i < 304; i += 256) {
        if (i < NWIN) {
            const int l = i / 49, r = i - l * 49;
            cIdx[i] = (unsigned short)(169 * l + 13 * (r / 7) + (r - (r / 7) * 7));
        } else cIdx[i] = 0;
    }
    __syncthreads();

    const float scale = 0.17677669529663687f;
    const unsigned short* Qg = Qb + (size_t)bh * (NWIN * DH);
    unsigned short* Pw = Pc + w * (16 * 32);

#pragma unroll
    for (int r5 = 0; r5 < 5; ++r5) {
        const int it = 4 * r5 + w;
        if (it < 19) {
            short8 qf;
            const int qrow = it * 16 + l15;
            if (qrow < NWIN) qf = *(const short8*)(Qg + qrow * DH + quad * 8);
            else             qf = (short8){0,0,0,0,0,0,0,0};

            f32x4 S[19];
#pragma unroll
            for (int jt = 0; jt < 19; ++jt) {
                const short8 bf = *(const short8*)(Ks + (jt * 16 + l15) * 32 + quad * 8);
                S[jt] = __builtin_amdgcn_mfma_f32_16x16x32_bf16(qf, bf, (f32x4){0.f,0.f,0.f,0.f}, 0, 0, 0);
            }

            int cj[19];
#pragma unroll
            for (int jt = 0; jt < 19; ++jt) cj[jt] = cIdx[jt * 16 + l15];

            const int rowb = it * 16 + quad * 4;
            float inv[4];
#pragma unroll
            for (int r = 0; r < 4; ++r) {
                const int ci = (int)cIdx[rowb + r] + 929;
                float m = -1e30f;
#pragma unroll
                for (int jt = 0; jt < 19; ++jt) {
                    float s = S[jt][r] * scale + biasH[ci - cj[jt]];
                    if (jt == 18 && l15 >= 6) s = -1e30f;
                    S[jt][r] = s;
                    m = fmaxf(m, s);
                }
                m = fmaxf(m, __shfl_xor(m, 1));
                m = fmaxf(m, __shfl_xor(m, 2));
                m = fmaxf(m, __shfl_xor(m, 4));
                m = fmaxf(m, __shfl_xor(m, 8));
                float lsum = 0.f;
#pragma unroll
                for (int jt = 0; jt < 19; ++jt) {
                    const float p = __expf(S[jt][r] - m);
                    S[jt][r] = p;
                    lsum += p;
                }
                lsum += __shfl_xor(lsum, 1);
                lsum += __shfl_xor(lsum, 2);
                lsum += __shfl_xor(lsum, 4);
                lsum += __shfl_xor(lsum, 8);
                inv[r] = 1.0f / lsum;
            }

            f32x4 o0 = {0.f,0.f,0.f,0.f}, o1 = {0.f,0.f,0.f,0.f};
#pragma unroll
            for (int kt = 0; kt < 10; ++kt) {
                const int jt0 = 2 * kt, jt1 = 2 * kt + 1;
#pragma unroll
                for (int r = 0; r < 4; ++r) {
                    Pw[(quad * 4 + r) * 32 + l15]      = f2bf(S[jt0][r]);
                    Pw[(quad * 4 + r) * 32 + 16 + l15] = (jt1 < 19) ? f2bf(S[jt1][r]) : (unsigned short)0;
                }
                __asm__ volatile("s_waitcnt lgkmcnt(0)" ::: "memory");
                const short8 pa = *(const short8*)(Pw + l15 * 32 + quad * 8);
                const short8 v0 = *(const short8*)(Vts + l15 * 328 + kt * 32 + quad * 8);
                const short8 v1 = *(const short8*)(Vts + (16 + l15) * 328 + kt * 32 + quad * 8);
                o0 = __builtin_amdgcn_mfma_f32_16x16x32_bf16(pa, v0, o0, 0, 0, 0);
                o1 = __builtin_amdgcn_mfma_f32_16x16x32_bf16(pa, v1, o1, 0, 0, 0);
                __asm__ volatile("s_waitcnt lgkmcnt(0)" ::: "memory");
            }

#pragma unroll
            for (int r = 0; r < 4; ++r) {
                const int rg = it * 16 + quad * 4 + r;
                if (rg < NWIN) {
                    unsigned short* op = Ob + ((size_t)bwin * NWIN + rg) * DIM + h * DH;
                    op[l15]      = f2bf(o0[r] * inv[r]);
                    op[16 + l15] = f2bf(o1[r] * inv[r]);
                }
            }
        }
    }
}

// ---------------------------------------------------------------------------
// Kernel 3: output projection, bf16 MFMA + fp32 scatter to final layout.
//   out = Ob(MPAD x 256) @ Wot^T (256 x 256)
// ---------------------------------------------------------------------------
__global__ __launch_bounds__(256) void gemm_out(
    const unsigned short* __restrict__ Ob, const unsigned short* __restrict__ Wot,
    float* __restrict__ out)
{
    __shared__ __align__(16) unsigned short As[128 * 64];
    __shared__ __align__(16) unsigned short Bs[128 * 64];

    const int bn = blockIdx.x & 1;
    const int bm = blockIdx.x >> 1;
    const int tileM = bm * 128;
    const int tileN = bn * 128;

    const int t    = threadIdx.x;
    const int w    = t >> 6;
    const int lane = t & 63;
    const int quad = lane >> 4;
    const int l15  = lane & 15;
    const int wm   = w >> 1, wn = w & 1;

    const int rA = lane >> 3;
    const int kA = (lane & 7) * 8;
    const unsigned short* aBase = Ob  + ((size_t)tileM + rA) * 256 + kA;
    const unsigned short* bBase = Wot + ((size_t)tileN + rA) * 256 + kA;

    f32x4 acc[4][4] = {};

    for (int kb = 0; kb < 4; ++kb) {
        const int k0 = kb * 64;
        __syncthreads();
#pragma unroll
        for (int i = 0; i < 4; ++i) {
            const int c = w * 4 + i;
            gl_lds16(aBase + (size_t)c * 8 * 256 + k0, &As[c * 512]);
            gl_lds16(bBase + (size_t)c * 8 * 256 + k0, &Bs[c * 512]);
        }
        __syncthreads();
#pragma unroll
        for (int c2 = 0; c2 < 2; ++c2) {
            const int kk = c2 * 32 + quad * 8;
            short8 a[4], b[4];
#pragma unroll
            for (int mi = 0; mi < 4; ++mi)
                a[mi] = *(const short8*)&As[(wm * 64 + mi * 16 + l15) * 64 + kk];
#pragma unroll
            for (int ni = 0; ni < 4; ++ni)
                b[ni] = *(const short8*)&Bs[(wn * 64 + ni * 16 + l15) * 64 + kk];
#pragma unroll
            for (int mi = 0; mi < 4; ++mi)
#pragma unroll
                for (int ni = 0; ni < 4; ++ni)
                    acc[mi][ni] = __builtin_amdgcn_mfma_f32_16x16x32_bf16(a[mi], b[ni], acc[mi][ni], 0, 0, 0);
        }
    }

    const int colB = tileN + wn * 64;
    const int rowB = tileM + wm * 64 + quad * 4;
#pragma unroll
    for (int mi = 0; mi < 4; ++mi) {
#pragma unroll
        for (int r = 0; r < 4; ++r) {
            const int row = rowB + mi * 16 + r;
            if (row < MROWS) {
                const int bw = row / NWIN, rw = row - bw * NWIN;
                const int bb = bw / 144,  r2 = bw - bb * 144;
                const int gxi = r2 / 12,  gyi = r2 - gxi * 12;
                const int lz = rw / 49,   r3 = rw - lz * 49;
                const int wa = r3 / 7,    wb = r3 - wa * 7;
                float* orow = out + ((((((size_t)bb * 6 + lz) * 12 + gxi) * 12 + gyi) * 7 + wa) * 7 + wb) * DIM;
#pragma unroll
                for (int ni = 0; ni < 4; ++ni)
                    orow[colB + ni * 16 + l15] = acc[mi][ni][r];
            }
        }
    }
}

// ---------------------------------------------------------------------------
extern "C" void kernel_launch(void* const* d_in, const int* in_sizes, int n_in,
                              void* d_out, int out_size, void* d_ws, size_t ws_size,
                              hipStream_t stream)
{
    const float* x          = (const float*)d_in[0];
    const float* Wq         = (const float*)d_in[1];
    const float* bq         = (const float*)d_in[2];
    const float* Wkv        = (const float*)d_in[3];
    const float* bkv        = (const float*)d_in[4];
    const float* Wout       = (const float*)d_in[5];
    const float* bias_table = (const float*)d_in[6];
    float* out = (float*)d_out;

    const size_t planePad = (size_t)MPAD * DIM;    // padded bf16 plane elems
    const size_t plane    = (size_t)MROWS * DIM;
    unsigned short* Xb  = (unsigned short*)d_ws;
    unsigned short* Qb  = Xb + planePad;
    unsigned short* Kb  = Qb + plane;
    unsigned short* Vtb = Kb + plane;
    unsigned short* Ob  = Vtb + plane;
    unsigned short* Wt  = Ob + planePad;
    unsigned short* Wot = Wt + 768 * 256;

    prep_x<<<MPAD / 8, 256, 0, stream>>>(x, Xb);
    prep_w<<<1024, 256, 0, stream>>>(Wq, Wkv, Wout, Wt, Wot);
    gemm_qkv<<<662 * 6, 256, 0, stream>>>(Xb, Wt, bq, bkv, Qb, Kb, Vtb);
    attn_kernel<<<BWIN * NHEADS, 256, 0, stream>>>(Qb, Kb, Vtb, bias_table, Ob);
    gemm_out<<<662 * 2, 256, 0, stream>>>(Ob, Wot, out);
}

// Round 6
// 437.989 us; speedup vs baseline: 4.2901x; 1.0132x over previous
//
#include <hip/hip_runtime.h>
#include <hip/hip_bf16.h>

// Problem constants
#define DIM    256
#define NWIN   294            // tokens per window = 6*7*7
#define BWIN   288            // windows = 2*12*12
#define MROWS  (BWIN * NWIN)  // 84672 total tokens
#define MPAD   84736          // 662 * 128 (M padded for 128-row tiles)
#define NHEADS 8
#define DH     32
#define NBIAS  1859           // 11*13*13

typedef __attribute__((ext_vector_type(8))) short  short8;  // 8 bf16 = 4 VGPRs
typedef __attribute__((ext_vector_type(4))) float  f32x4;

__device__ __forceinline__ unsigned short f2bf(float f) {
    unsigned int u = __float_as_uint(f);
    u += 0x7FFFu + ((u >> 16) & 1u);     // round-to-nearest-even
    return (unsigned short)(u >> 16);
}

__device__ __forceinline__ unsigned pk2bf(float a, float b) {
    __hip_bfloat162 h = __float22bfloat162_rn(float2{a, b});  // v_cvt_pk_bf16_f32
    unsigned u;
    __builtin_memcpy(&u, &h, 4);
    return u;
}

// async global->LDS, 16B per lane. LDS dest = wave-uniform base + lane*16.
__device__ __forceinline__ void gl_lds16(const void* g, void* l) {
    __builtin_amdgcn_global_load_lds((const __attribute__((address_space(1))) unsigned int*)g,
                                     (__attribute__((address_space(3))) unsigned int*)l,
                                     16, 0, 0);
}

// ---------------------------------------------------------------------------
// Prep A: gather + cast x -> Xb bf16 (MPAD x 256) row-major in (B*n, d) order.
// ---------------------------------------------------------------------------
__global__ __launch_bounds__(256) void prep_x(const float* __restrict__ x,
                                              unsigned short* __restrict__ Xb)
{
    const int g   = blockIdx.x * 256 + threadIdx.x;
    const int row = g >> 5;
    const int col = (g & 31) * 8;
    if (row >= MPAD) return;
    uint4 pk;
    if (row < MROWS) {
        const int bw = row / NWIN, rw = row - bw * NWIN;
        const int bb = bw / 144,  r2 = bw - bb * 144;
        const int gxi = r2 / 12,  gyi = r2 - gxi * 12;
        const int lz = rw / 49,   r3 = rw - lz * 49;
        const int wa = r3 / 7,    wb = r3 - wa * 7;
        const float* src = x + ((((((size_t)bb * 6 + lz) * 12 + gxi) * 12 + gyi) * 7 + wa) * 7 + wb) * DIM + col;
        const float4 f0 = *(const float4*)(src);
        const float4 f1 = *(const float4*)(src + 4);
        pk.x = pk2bf(f0.x, f0.y);
        pk.y = pk2bf(f0.z, f0.w);
        pk.z = pk2bf(f1.x, f1.y);
        pk.w = pk2bf(f1.z, f1.w);
    } else {
        pk = (uint4){0u, 0u, 0u, 0u};
    }
    *(uint4*)(Xb + (size_t)row * 256 + col) = pk;
}

// ---------------------------------------------------------------------------
// Prep B: cast + transpose weights to (N,K) bf16.
// ---------------------------------------------------------------------------
__global__ __launch_bounds__(256) void prep_w(const float* __restrict__ Wq,
                                              const float* __restrict__ Wkv,
                                              const float* __restrict__ Wout,
                                              unsigned short* __restrict__ Wt,
                                              unsigned short* __restrict__ Wot)
{
    const int g = blockIdx.x * 256 + threadIdx.x;
    if (g < 768 * 256) {
        const int n = g >> 8, k = g & 255;
        const float v = (n < 256) ? Wq[k * 256 + n] : Wkv[k * 512 + (n - 256)];
        Wt[g] = f2bf(v);
    } else {
        const int g2 = g - 768 * 256;
        const int n = g2 >> 8, k = g2 & 255;
        Wot[g2] = f2bf(Wout[k * 256 + n]);
    }
}

// ---------------------------------------------------------------------------
// Kernel 1: QKV projection, bf16 MFMA (m97 structure). Unchanged from R3.
// ---------------------------------------------------------------------------
__global__ __launch_bounds__(256) void gemm_qkv(
    const unsigned short* __restrict__ Xb, const unsigned short* __restrict__ Wt,
    const float* __restrict__ bq, const float* __restrict__ bkv,
    unsigned short* __restrict__ Qb, unsigned short* __restrict__ Kb,
    unsigned short* __restrict__ Vtb)
{
    __shared__ __align__(16) unsigned short As[128 * 64];
    __shared__ __align__(16) unsigned short Bs[128 * 64];

    const int bn = blockIdx.x % 6;
    const int bm = blockIdx.x / 6;
    const int tileM = bm * 128;
    const int tileN = bn * 128;

    const int t    = threadIdx.x;
    const int w    = t >> 6;
    const int lane = t & 63;
    const int quad = lane >> 4;
    const int l15  = lane & 15;
    const int wm   = w >> 1, wn = w & 1;

    const int rA = lane >> 3;
    const int kA = (lane & 7) * 8;
    const unsigned short* aBase = Xb + ((size_t)tileM + rA) * 256 + kA;
    const unsigned short* bBase = Wt + ((size_t)tileN + rA) * 256 + kA;

    f32x4 acc[4][4] = {};

    for (int kb = 0; kb < 4; ++kb) {
        const int k0 = kb * 64;
        __syncthreads();
#pragma unroll
        for (int i = 0; i < 4; ++i) {
            const int c = w * 4 + i;
            gl_lds16(aBase + (size_t)c * 8 * 256 + k0, &As[c * 512]);
            gl_lds16(bBase + (size_t)c * 8 * 256 + k0, &Bs[c * 512]);
        }
        __syncthreads();
#pragma unroll
        for (int c2 = 0; c2 < 2; ++c2) {
            const int kk = c2 * 32 + quad * 8;
            short8 a[4], b[4];
#pragma unroll
            for (int mi = 0; mi < 4; ++mi)
                a[mi] = *(const short8*)&As[(wm * 64 + mi * 16 + l15) * 64 + kk];
#pragma unroll
            for (int ni = 0; ni < 4; ++ni)
                b[ni] = *(const short8*)&Bs[(wn * 64 + ni * 16 + l15) * 64 + kk];
#pragma unroll
            for (int mi = 0; mi < 4; ++mi)
#pragma unroll
                for (int ni = 0; ni < 4; ++ni)
                    acc[mi][ni] = __builtin_amdgcn_mfma_f32_16x16x32_bf16(a[mi], b[ni], acc[mi][ni], 0, 0, 0);
        }
    }

    const int colB = tileN + wn * 64;
    float bias[4];
#pragma unroll
    for (int ni = 0; ni < 4; ++ni) {
        const int n = colB + ni * 16 + l15;
        bias[ni] = (n < 256) ? bq[n] : bkv[n - 256];
    }
    const int rowB = tileM + wm * 64 + quad * 4;
#pragma unroll
    for (int mi = 0; mi < 4; ++mi) {
#pragma unroll
        for (int r = 0; r < 4; ++r) {
            const int row = rowB + mi * 16 + r;
            if (row < MROWS) {
                const int bw = row / NWIN;
                const int rw = row - bw * NWIN;
#pragma unroll
                for (int ni = 0; ni < 4; ++ni) {
                    const int n = colB + ni * 16 + l15;
                    const unsigned short v = f2bf(acc[mi][ni][r] + bias[ni]);
                    const int ch = n & 255;
                    const int hd = ch >> 5, di = ch & 31;
                    if (n < 512) {
                        unsigned short* dst = (n < 256) ? Qb : Kb;
                        dst[((size_t)(bw * NHEADS + hd) * NWIN + rw) * DH + di] = v;
                    } else {
                        Vtb[((size_t)(bw * NHEADS + hd) * DH + di) * NWIN + rw] = v;
                    }
                }
            }
        }
    }
}

// ---------------------------------------------------------------------------
// Kernel 2: MFMA flash attention, S^T formulation.
//   S^T = K Q^T -> exp2 with fused bias (no max-sub, logits bounded ~1.5)
//   -> P^T->A via shuffles (both jt candidates pulled, select at DEST quad)
//   -> PV + lsum via mfma with ones-B.
// ---------------------------------------------------------------------------
__global__ __launch_bounds__(256, 3) void attn_kernel(
    const unsigned short* __restrict__ Qb, const unsigned short* __restrict__ Kb,
    const unsigned short* __restrict__ Vtb, const float* __restrict__ bias_table,
    unsigned short* __restrict__ Ob)
{
    const int bh   = blockIdx.x;      // 0..2303
    const int bwin = bh >> 3;
    const int h    = bh & 7;

    __shared__ __align__(16) unsigned short Ks[304 * 40];   // 24320 B, pitch 40 halves
    __shared__ __align__(16) unsigned short Vts[32 * 328];  // 20992 B, V^T pitch 328
    __shared__ float          biasHs[NBIAS];                // 7436 B (pre-scaled by log2e)
    __shared__ __align__(8) unsigned short cIdx[304];       // 608 B

    const int t    = threadIdx.x;
    const int w    = t >> 6;
    const int lane = t & 63;
    const int quad = lane >> 4;
    const int l15  = lane & 15;

    // ---- stage K with padded pitch (rows >= NWIN zeroed)
    {
        const unsigned short* Kg = Kb + (size_t)bh * (NWIN * DH);
        for (int i = t; i < 304 * 4; i += 256) {
            const int row = i >> 2, seg = i & 3;
            uint4 v = (uint4){0u, 0u, 0u, 0u};
            if (row < NWIN) v = *(const uint4*)(Kg + row * 32 + seg * 8);
            *(uint4*)(Ks + row * 40 + seg * 8) = v;
        }
    }
    // ---- stage V^T with zero pad cols
    {
        const unsigned short* Vg = Vtb + (size_t)bh * (DH * NWIN);
        for (int i = t; i < 32 * 328; i += 256) {
            const int r = i / 328, c = i - r * 328;
            Vts[i] = (c < NWIN) ? Vg[r * NWIN + c] : (unsigned short)0;
        }
    }
    // ---- bias column for this head, pre-multiplied by log2(e)
    for (int i = t; i < NBIAS; i += 256) biasHs[i] = bias_table[i * NHEADS + h] * 1.44269504088896f;
    // ---- coordinate codes (0 for pad)
    for (int i = t; i < 304; i += 256) {
        if (i < NWIN) {
            const int l = i / 49, r = i - l * 49;
            cIdx[i] = (unsigned short)(169 * l + 13 * (r / 7) + (r - (r / 7) * 7));
        } else cIdx[i] = 0;
    }
    __syncthreads();

    const float SL2E = 0.25503486f;   // (1/sqrt(32)) * log2(e)
    const unsigned short* Qg = Qb + (size_t)bh * (NWIN * DH);
    const int   srcB = ((quad & 1) << 5) + l15;   // source lane for P transform
    const bool  hiSel = (quad >= 2);              // DEST-side jt selection
    const short8 ones = (short8){0x3F80,0x3F80,0x3F80,0x3F80,0x3F80,0x3F80,0x3F80,0x3F80};

#pragma unroll
    for (int r5 = 0; r5 < 5; ++r5) {
        const int it = 4 * r5 + w;
        if (it < 19) {
            // ---- Q fragment for this query tile (B-operand; zero pad rows)
            short8 qf;
            const int qrow = it * 16 + l15;
            if (qrow < NWIN) qf = *(const short8*)(Qg + qrow * DH + quad * 8);
            else             qf = (short8){0,0,0,0,0,0,0,0};

            const int ciB = (int)cIdx[it * 16 + l15] + 929;   // query code (per lane)
            const float* bbase = biasHs + ciB;

            // ---- S^T = K Q^T : D(row=key quad*4+reg, col=query l15)
            f32x4 S[19];
#pragma unroll
            for (int jt = 0; jt < 19; ++jt) {
                const short8 kf = *(const short8*)(Ks + (jt * 16 + l15) * 40 + quad * 8);
                S[jt] = __builtin_amdgcn_mfma_f32_16x16x32_bf16(kf, qf, (f32x4){0.f,0.f,0.f,0.f}, 0, 0, 0);
            }

            // ---- p = exp2(s*SL2E + bias'); pack to bf16 pairs
            unsigned pk0[20], pk1[20];
            pk0[19] = 0u; pk1[19] = 0u;
#pragma unroll
            for (int jt = 0; jt < 19; ++jt) {
                const ushort4 c4 = *(const ushort4*)(cIdx + jt * 16 + quad * 4);
                float p0 = exp2f(fmaf(S[jt][0], SL2E, bbase[-(int)c4.x]));
                float p1 = exp2f(fmaf(S[jt][1], SL2E, bbase[-(int)c4.y]));
                float p2 = exp2f(fmaf(S[jt][2], SL2E, bbase[-(int)c4.z]));
                float p3 = exp2f(fmaf(S[jt][3], SL2E, bbase[-(int)c4.w]));
                if (jt == 18) {     // mask pad keys (288 + quad*4 + r >= 294)
                    if (quad * 4 + 0 >= 6) p0 = 0.f;
                    if (quad * 4 + 1 >= 6) p1 = 0.f;
                    if (quad * 4 + 2 >= 6) p2 = 0.f;
                    if (quad * 4 + 3 >= 6) p3 = 0.f;
                }
                pk0[jt] = pk2bf(p0, p1);
                pk1[jt] = pk2bf(p2, p3);
            }

            // ---- O = P V, lsum = P 1.
            // A-operand needs P[query=l15][key=kt*32+quad*8+j]. Each source lane
            // serves one jt0-consumer and one jt1-consumer, so pull BOTH jt
            // candidates and select with the destination's hiSel.
            f32x4 o0 = {0.f,0.f,0.f,0.f}, o1 = {0.f,0.f,0.f,0.f}, o2 = {0.f,0.f,0.f,0.f};
#pragma unroll
            for (int kt = 0; kt < 10; ++kt) {
                const int e0 = (int)pk0[2 * kt], e1 = (int)pk0[2 * kt + 1];
                const int f0 = (int)pk1[2 * kt], f1 = (int)pk1[2 * kt + 1];
                const unsigned aLo = (unsigned)__shfl(e0, srcB);
                const unsigned aHi = (unsigned)__shfl(e1, srcB);
                const unsigned bLo = (unsigned)__shfl(f0, srcB);
                const unsigned bHi = (unsigned)__shfl(f1, srcB);
                const unsigned cLo = (unsigned)__shfl(e0, srcB + 16);
                const unsigned cHi = (unsigned)__shfl(e1, srcB + 16);
                const unsigned dLo = (unsigned)__shfl(f0, srcB + 16);
                const unsigned dHi = (unsigned)__shfl(f1, srcB + 16);
                uint4 pw;
                pw.x = hiSel ? aHi : aLo;
                pw.y = hiSel ? bHi : bLo;
                pw.z = hiSel ? cHi : cLo;
                pw.w = hiSel ? dHi : dLo;
                short8 pa;
                __builtin_memcpy(&pa, &pw, 16);
                const short8 v0 = *(const short8*)(Vts + l15 * 328 + kt * 32 + quad * 8);
                const short8 v1 = *(const short8*)(Vts + (16 + l15) * 328 + kt * 32 + quad * 8);
                o0 = __builtin_amdgcn_mfma_f32_16x16x32_bf16(pa, v0, o0, 0, 0, 0);
                o1 = __builtin_amdgcn_mfma_f32_16x16x32_bf16(pa, v1, o1, 0, 0, 0);
                o2 = __builtin_amdgcn_mfma_f32_16x16x32_bf16(pa, ones, o2, 0, 0, 0);
            }

            // ---- normalize + store bf16 (row=query=quad*4+r, col d = l15 / 16+l15)
#pragma unroll
            for (int r = 0; r < 4; ++r) {
                const int rg = it * 16 + quad * 4 + r;
                if (rg < NWIN) {
                    const float inv = 1.0f / o2[r];
                    unsigned short* op = Ob + ((size_t)bwin * NWIN + rg) * DIM + h * DH;
                    op[l15]      = f2bf(o0[r] * inv);
                    op[16 + l15] = f2bf(o1[r] * inv);
                }
            }
        }
    }
}

// ---------------------------------------------------------------------------
// Kernel 3: output projection, bf16 MFMA + fp32 scatter. Unchanged from R3.
// ---------------------------------------------------------------------------
__global__ __launch_bounds__(256) void gemm_out(
    const unsigned short* __restrict__ Ob, const unsigned short* __restrict__ Wot,
    float* __restrict__ out)
{
    __shared__ __align__(16) unsigned short As[128 * 64];
    __shared__ __align__(16) unsigned short Bs[128 * 64];

    const int bn = blockIdx.x & 1;
    const int bm = blockIdx.x >> 1;
    const int tileM = bm * 128;
    const int tileN = bn * 128;

    const int t    = threadIdx.x;
    const int w    = t >> 6;
    const int lane = t & 63;
    const int quad = lane >> 4;
    const int l15  = lane & 15;
    const int wm   = w >> 1, wn = w & 1;

    const int rA = lane >> 3;
    const int kA = (lane & 7) * 8;
    const unsigned short* aBase = Ob  + ((size_t)tileM + rA) * 256 + kA;
    const unsigned short* bBase = Wot + ((size_t)tileN + rA) * 256 + kA;

    f32x4 acc[4][4] = {};

    for (int kb = 0; kb < 4; ++kb) {
        const int k0 = kb * 64;
        __syncthreads();
#pragma unroll
        for (int i = 0; i < 4; ++i) {
            const int c = w * 4 + i;
            gl_lds16(aBase + (size_t)c * 8 * 256 + k0, &As[c * 512]);
            gl_lds16(bBase + (size_t)c * 8 * 256 + k0, &Bs[c * 512]);
        }
        __syncthreads();
#pragma unroll
        for (int c2 = 0; c2 < 2; ++c2) {
            const int kk = c2 * 32 + quad * 8;
            short8 a[4], b[4];
#pragma unroll
            for (int mi = 0; mi < 4; ++mi)
                a[mi] = *(const short8*)&As[(wm * 64 + mi * 16 + l15) * 64 + kk];
#pragma unroll
            for (int ni = 0; ni < 4; ++ni)
                b[ni] = *(const short8*)&Bs[(wn * 64 + ni * 16 + l15) * 64 + kk];
#pragma unroll
            for (int mi = 0; mi < 4; ++mi)
#pragma unroll
                for (int ni = 0; ni < 4; ++ni)
                    acc[mi][ni] = __builtin_amdgcn_mfma_f32_16x16x32_bf16(a[mi], b[ni], acc[mi][ni], 0, 0, 0);
        }
    }

    const int colB = tileN + wn * 64;
    const int rowB = tileM + wm * 64 + quad * 4;
#pragma unroll
    for (int mi = 0; mi < 4; ++mi) {
#pragma unroll
        for (int r = 0; r < 4; ++r) {
            const int row = rowB + mi * 16 + r;
            if (row < MROWS) {
                const int bw = row / NWIN, rw = row - bw * NWIN;
                const int bb = bw / 144,  r2 = bw - bb * 144;
                const int gxi = r2 / 12,  gyi = r2 - gxi * 12;
                const int lz = rw / 49,   r3 = rw - lz * 49;
                const int wa = r3 / 7,    wb = r3 - wa * 7;
                float* orow = out + ((((((size_t)bb * 6 + lz) * 12 + gxi) * 12 + gyi) * 7 + wa) * 7 + wb) * DIM;
#pragma unroll
                for (int ni = 0; ni < 4; ++ni)
                    orow[colB + ni * 16 + l15] = acc[mi][ni][r];
            }
        }
    }
}

// ---------------------------------------------------------------------------
extern "C" void kernel_launch(void* const* d_in, const int* in_sizes, int n_in,
                              void* d_out, int out_size, void* d_ws, size_t ws_size,
                              hipStream_t stream)
{
    const float* x          = (const float*)d_in[0];
    const float* Wq         = (const float*)d_in[1];
    const float* bq         = (const float*)d_in[2];
    const float* Wkv        = (const float*)d_in[3];
    const float* bkv        = (const float*)d_in[4];
    const float* Wout       = (const float*)d_in[5];
    const float* bias_table = (const float*)d_in[6];
    float* out = (float*)d_out;

    const size_t planePad = (size_t)MPAD * DIM;
    const size_t plane    = (size_t)MROWS * DIM;
    unsigned short* Xb  = (unsigned short*)d_ws;
    unsigned short* Qb  = Xb + planePad;
    unsigned short* Kb  = Qb + plane;
    unsigned short* Vtb = Kb + plane;
    unsigned short* Ob  = Vtb + plane;
    unsigned short* Wt  = Ob + planePad;
    unsigned short* Wot = Wt + 768 * 256;

    prep_x<<<MPAD / 8, 256, 0, stream>>>(x, Xb);
    prep_w<<<1024, 256, 0, stream>>>(Wq, Wkv, Wout, Wt, Wot);
    gemm_qkv<<<662 * 6, 256, 0, stream>>>(Xb, Wt, bq, bkv, Qb, Kb, Vtb);
    attn_kernel<<<BWIN * NHEADS, 256, 0, stream>>>(Qb, Kb, Vtb, bias_table, Ob);
    gemm_out<<<662 * 2, 256, 0, stream>>>(Ob, Wot, out);
}